// Round 2
// baseline (602.076 us; speedup 1.0000x reference)
//
#include <hip/hip_runtime.h>
#include <hip/hip_bf16.h>
#include <stdint.h>

typedef __bf16 bf16x8 __attribute__((ext_vector_type(8)));
typedef float  f32x4  __attribute__((ext_vector_type(4)));
typedef unsigned short u16x8 __attribute__((ext_vector_type(8)));

// ---- helpers ---------------------------------------------------------------

__device__ __forceinline__ unsigned short f32_to_bf16_rne(float f) {
  union { float f; unsigned int u; } v; v.f = f;
  unsigned int u = v.u;
  unsigned int r = u + 0x7fffu + ((u >> 16) & 1u);  // round-to-nearest-even
  return (unsigned short)(r >> 16);
}

// async global->LDS, 16B per lane. LDS dest is wave-uniform base; HW scatters
// lane i at base + i*16 (guide §5 caveat, m104/m108).
__device__ __forceinline__ void async16(const unsigned short* g, unsigned short* l) {
  __builtin_amdgcn_global_load_lds(
      (const __attribute__((address_space(1))) unsigned int*)g,
      (__attribute__((address_space(3))) unsigned int*)l,
      16, 0, 0);
}

// ---- kernel 1: W' = W + 2*(lora_B @ lora_A), cast to bf16 ------------------
__global__ __launch_bounds__(256) void make_wp(const float* __restrict__ W,
                                               const float* __restrict__ lA,
                                               const float* __restrict__ lB,
                                               unsigned short* __restrict__ Wp) {
  const int o   = blockIdx.x;      // 0..4095
  const int tid = threadIdx.x;     // 0..255
  __shared__ float sB[16];
  if (tid < 16) sB[tid] = lB[o * 16 + tid] * 2.0f;  // fold SCALING=2.0
  __syncthreads();
  #pragma unroll
  for (int it = 0; it < 4; ++it) {
    const int k = (it * 256 + tid) * 4;
    float4 acc = *(const float4*)(W + (size_t)o * 4096 + k);
    #pragma unroll
    for (int r = 0; r < 16; ++r) {
      const float4 a = *(const float4*)(lA + (size_t)r * 4096 + k);
      const float s = sB[r];
      acc.x += s * a.x; acc.y += s * a.y; acc.z += s * a.z; acc.w += s * a.w;
    }
    ushort4 ov;
    ov.x = f32_to_bf16_rne(acc.x);
    ov.y = f32_to_bf16_rne(acc.y);
    ov.z = f32_to_bf16_rne(acc.z);
    ov.w = f32_to_bf16_rne(acc.w);
    *(ushort4*)(Wp + (size_t)o * 4096 + k) = ov;
  }
}

// ---- kernel 2 (fast path only): cast x fp32 -> bf16 ------------------------
__global__ __launch_bounds__(256) void cast_x(const float* __restrict__ x,
                                              unsigned short* __restrict__ xb,
                                              int n8) {
  const int idx = blockIdx.x * 256 + threadIdx.x;
  if (idx >= n8) return;
  const float4* p = (const float4*)x + (size_t)idx * 2;
  const float4 f0 = p[0], f1 = p[1];
  u16x8 o;
  o[0] = f32_to_bf16_rne(f0.x); o[1] = f32_to_bf16_rne(f0.y);
  o[2] = f32_to_bf16_rne(f0.z); o[3] = f32_to_bf16_rne(f0.w);
  o[4] = f32_to_bf16_rne(f1.x); o[5] = f32_to_bf16_rne(f1.y);
  o[6] = f32_to_bf16_rne(f1.z); o[7] = f32_to_bf16_rne(f1.w);
  *((u16x8*)xb + idx) = o;
}

// ---- kernel 3: out[M,N] = A[M,K] @ Wp[N,K]^T + bias ------------------------
// m97 structure: 128x128 tile, BK=32, 4 waves 2x2, 4x4 16x16x32 bf16 frags,
// 2-barrier K-loop. A_F32=false: A is bf16, async16-staged (needs 96MB ws).
// A_F32=true: A is f32 (x itself), staged via global_load->cvt->ds_write into
// the SAME bf16 LDS layout, so the read/MFMA path is identical & m97-proven.
#define BM 128
#define BN 128
#define BK 32
#define GEMM_M 8192
#define GEMM_N 4096
#define GEMM_K 4096

template <bool A_F32>
__global__ __launch_bounds__(256) void gemm_bias(
    const void* __restrict__ Aptr,          // [M,K] bf16 bits or f32
    const unsigned short* __restrict__ B,   // [N,K] bf16 bits (Wp)
    const float* __restrict__ bias,         // [N]
    float* __restrict__ C) {                // [M,N] fp32
  // LDS tiles: [128 rows][32 k] bf16, contiguous, NO padding (global_load_lds
  // scatter order == lane order; ds_write path mirrors the same layout).
  __shared__ __align__(16) unsigned short sA[BM * BK];
  __shared__ __align__(16) unsigned short sB[BM * BK];

  const int tid  = threadIdx.x;
  const int wave = tid >> 6;
  const int lane = tid & 63;

  // staging map: thread tid -> row tid>>2 (0..63), col (tid&3)*8 (bf16 elems);
  // LDS offset == tid*8 shorts within each 64-row half.
  const int srow = tid >> 2;
  const int scol = (tid & 3) << 3;

  const size_t a_row0 = (size_t)blockIdx.y * BM;
  const size_t b_row0 = (size_t)blockIdx.x * BN;

  const unsigned short* bg0 = B + (b_row0 +      srow) * GEMM_K + scol;
  const unsigned short* bg1 = B + (b_row0 + 64 + srow) * GEMM_K + scol;

  // wave-uniform LDS bases for async16 (wave w: lanes land at base + lane*16B)
  unsigned short* sA0 = sA +        wave * 512;
  unsigned short* sA1 = sA + 2048 + wave * 512;
  unsigned short* sB0 = sB +        wave * 512;
  unsigned short* sB1 = sB + 2048 + wave * 512;

  // A pointers per variant
  const unsigned short* ag0 = nullptr; const unsigned short* ag1 = nullptr;
  const float* af0 = nullptr; const float* af1 = nullptr;
  if constexpr (A_F32) {
    af0 = (const float*)Aptr + (a_row0 +      srow) * GEMM_K + scol;
    af1 = (const float*)Aptr + (a_row0 + 64 + srow) * GEMM_K + scol;
  } else {
    ag0 = (const unsigned short*)Aptr + (a_row0 +      srow) * GEMM_K + scol;
    ag1 = (const unsigned short*)Aptr + (a_row0 + 64 + srow) * GEMM_K + scol;
  }
  // per-thread ds_write dests for the f32 variant (same layout as async16)
  unsigned short* sAw0 = sA +        tid * 8;
  unsigned short* sAw1 = sA + 2048 + tid * 8;

  // compute-phase map: wave (wm,wn) 2x2, 64x64 per wave
  const int wm   = (wave >> 1) * 64;
  const int wn   = (wave & 1) * 64;
  const int lrow = lane & 15;
  const int lk   = (lane >> 4) * 8;

  const unsigned short* sa_rd = sA + (wm + lrow) * BK + lk;
  const unsigned short* sb_rd = sB + (wn + lrow) * BK + lk;

  f32x4 acc[4][4];
  #pragma unroll
  for (int i = 0; i < 4; ++i)
    #pragma unroll
    for (int j = 0; j < 4; ++j)
      acc[i][j] = (f32x4){0.f, 0.f, 0.f, 0.f};

  for (int k0 = 0; k0 < GEMM_K; k0 += BK) {
    __syncthreads();   // prior iter's LDS reads done before overwrite
    async16(bg0 + k0, sB0);
    async16(bg1 + k0, sB1);
    if constexpr (A_F32) {
      const float* p0 = af0 + k0;
      const float* p1 = af1 + k0;
      const float4 x0 = *(const float4*)(p0);
      const float4 x1 = *(const float4*)(p0 + 4);
      const float4 y0 = *(const float4*)(p1);
      const float4 y1 = *(const float4*)(p1 + 4);
      u16x8 w0, w1;
      w0[0] = f32_to_bf16_rne(x0.x); w0[1] = f32_to_bf16_rne(x0.y);
      w0[2] = f32_to_bf16_rne(x0.z); w0[3] = f32_to_bf16_rne(x0.w);
      w0[4] = f32_to_bf16_rne(x1.x); w0[5] = f32_to_bf16_rne(x1.y);
      w0[6] = f32_to_bf16_rne(x1.z); w0[7] = f32_to_bf16_rne(x1.w);
      w1[0] = f32_to_bf16_rne(y0.x); w1[1] = f32_to_bf16_rne(y0.y);
      w1[2] = f32_to_bf16_rne(y0.z); w1[3] = f32_to_bf16_rne(y0.w);
      w1[4] = f32_to_bf16_rne(y1.x); w1[5] = f32_to_bf16_rne(y1.y);
      w1[6] = f32_to_bf16_rne(y1.z); w1[7] = f32_to_bf16_rne(y1.w);
      *(u16x8*)sAw0 = w0;
      *(u16x8*)sAw1 = w1;
    } else {
      async16(ag0 + k0, sA0);
      async16(ag1 + k0, sA1);
    }
    __syncthreads();   // compiler drains vmcnt/lgkmcnt before s_barrier

    bf16x8 af[4], bf[4];
    #pragma unroll
    for (int i = 0; i < 4; ++i) {
      af[i] = *(const bf16x8*)(sa_rd + i * 16 * BK);
      bf[i] = *(const bf16x8*)(sb_rd + i * 16 * BK);
    }
    #pragma unroll
    for (int i = 0; i < 4; ++i)
      #pragma unroll
      for (int j = 0; j < 4; ++j)
        acc[i][j] = __builtin_amdgcn_mfma_f32_16x16x32_bf16(af[i], bf[j], acc[i][j], 0, 0, 0);
  }

  // epilogue: C/D layout col=lane&15, row=(lane>>4)*4+reg (m89-verified)
  const int row0 = (int)a_row0 + wm + (lane >> 4) * 4;
  const int col0 = (int)b_row0 + wn + lrow;
  float bv[4];
  #pragma unroll
  for (int j = 0; j < 4; ++j) bv[j] = bias[col0 + j * 16];
  #pragma unroll
  for (int i = 0; i < 4; ++i)
    #pragma unroll
    for (int j = 0; j < 4; ++j) {
      const int col = col0 + j * 16;
      #pragma unroll
      for (int r = 0; r < 4; ++r) {
        const int row = row0 + i * 16 + r;
        C[(size_t)row * GEMM_N + col] = acc[i][j][r] + bv[j];
      }
    }
}

// ---- launch ----------------------------------------------------------------

extern "C" void kernel_launch(void* const* d_in, const int* in_sizes, int n_in,
                              void* d_out, int out_size, void* d_ws, size_t ws_size,
                              hipStream_t stream) {
  const float* x  = (const float*)d_in[0];   // [4,2048,4096]
  const float* W  = (const float*)d_in[1];   // [4096,4096]
  const float* b  = (const float*)d_in[2];   // [4096]
  const float* lA = (const float*)d_in[3];   // [16,4096]
  const float* lB = (const float*)d_in[4];   // [4096,16]
  float* out = (float*)d_out;                // [4,2048,4096] fp32
  (void)in_sizes; (void)n_in; (void)out_size;

  // ws layout: Wp bf16 [4096*4096] = 32MiB; fast path also xb bf16 [8192*4096]
  // = 64MiB at offset 32MiB. Branch on ws_size (constant per session -> same
  // work every call). Round-0 bug: we assumed 96MiB and likely wrote past ws.
  const size_t WP_BYTES = (size_t)4096 * 4096 * 2;                 // 33554432
  const size_t XB_BYTES = (size_t)8192 * 4096 * 2;                 // 67108864
  unsigned short* Wp = (unsigned short*)d_ws;

  make_wp<<<4096, 256, 0, stream>>>(W, lA, lB, Wp);

  if (ws_size >= WP_BYTES + XB_BYTES) {
    unsigned short* xb = Wp + (size_t)4096 * 4096;
    cast_x<<<(4194304 + 255) / 256, 256, 0, stream>>>(x, xb, 4194304);
    gemm_bias<false><<<dim3(GEMM_N / BN, GEMM_M / BM), 256, 0, stream>>>(
        (const void*)xb, Wp, b, out);
  } else {
    gemm_bias<true><<<dim3(GEMM_N / BN, GEMM_M / BM), 256, 0, stream>>>(
        (const void*)x, Wp, b, out);
  }
}